// Round 1
// baseline (189.530 us; speedup 1.0000x reference)
//
#include <hip/hip_runtime.h>
#include <hip/hip_bf16.h>

typedef __attribute__((ext_vector_type(8))) short bf16x8;
typedef __attribute__((ext_vector_type(4))) float f32x4;

#define XF_H   65
#define XF_W   66          // padded row stride (elements)
#define PLANE  (XF_H * XF_W)   // 4290
#define KDIM   2304
#define NDIM   16384
#define OUT_PER_B (256 * 1024)  // 262144

static __device__ __forceinline__ ushort f2bf(float f) {
  union { float f; unsigned int i; } v; v.f = f;
  unsigned int x = v.i;
  x += 0x7fffu + ((x >> 16) & 1u);   // round-to-nearest-even
  return (ushort)(x >> 16);
}

// ---------------- Kernel 1: separable 4x4 FIR, pad 2, f32 -> bf16 ----------------
// one block per (b,c) plane; 64x64 in -> 65x65 out (row stride XF_W)
__global__ __launch_bounds__(256) void k_fir(const float* __restrict__ x,
                                             ushort* __restrict__ xf) {
  __shared__ float sx[64 * 64];
  __shared__ float st[64 * 65];
  const int plane = blockIdx.x;               // 0..4095
  const float* xp = x + (size_t)plane * 4096;
  ushort* op = xf + (size_t)plane * PLANE;
  const int t = threadIdx.x;

  const float4* x4 = (const float4*)xp;
  float4* s4 = (float4*)sx;
#pragma unroll
  for (int i = 0; i < 4; ++i) s4[t + 256 * i] = x4[t + 256 * i];
  __syncthreads();

  const float fc[4] = {1.f, 3.f, 3.f, 1.f};

  // horizontal pass: st[i][j] = sum_v fc[v]*x[i][j+v-2], j in [0,65)
  for (int idx = t; idx < 64 * 65; idx += 256) {
    int i = idx / 65, j = idx - i * 65;
    float a = 0.f;
#pragma unroll
    for (int v = 0; v < 4; ++v) {
      int col = j + v - 2;
      if (col >= 0 && col < 64) a += fc[v] * sx[i * 64 + col];
    }
    st[idx] = a;
  }
  __syncthreads();

  // vertical pass + 1/64 normalization
  for (int idx = t; idx < 65 * 65; idx += 256) {
    int i = idx / 65, j = idx - i * 65;
    float a = 0.f;
#pragma unroll
    for (int u = 0; u < 4; ++u) {
      int r = i + u - 2;
      if (r >= 0 && r < 64) a += fc[u] * st[r * 65 + j];
    }
    op[i * XF_W + j] = f2bf(a * 0.015625f);
  }
}

// ---------------- Kernel 2: w f32 -> bf16 (layout already [oc][ic*9+kh*3+kw]) ---
__global__ __launch_bounds__(256) void k_wcast(const float* __restrict__ w,
                                               ushort* __restrict__ wb) {
  int i = blockIdx.x * 256 + threadIdx.x;     // 147456 float4s total
  float4 v = ((const float4*)w)[i];
  ushort4 o;
  o.x = f2bf(v.x); o.y = f2bf(v.y); o.z = f2bf(v.z); o.w = f2bf(v.w);
  ((ushort4*)wb)[i] = o;
}

// ---------------- Kernel 3: im2col (transposed): XcolT[n][k] ---------------------
// n = (b*32+oh)*32+ow,  k = ic*9 + kh*3 + kw,  value = xf[b][ic][2oh+kh][2ow+kw]
__global__ __launch_bounds__(256) void k_im2col(const ushort* __restrict__ xf,
                                                ushort* __restrict__ xc) {
  const int n = blockIdx.x;                   // 0..16383
  const int b = n >> 10, oh = (n >> 5) & 31, ow = n & 31;
  const ushort* base = xf + (size_t)b * 256 * PLANE + (2 * oh) * XF_W + 2 * ow;
  ushort* q = xc + (size_t)n * KDIM;
  for (int k = threadIdx.x; k < KDIM; k += 256) {
    int ic = k / 9;
    int j = k - ic * 9;
    int dh = j / 3;
    int dw = j - dh * 3;
    q[k] = base[(size_t)ic * PLANE + dh * XF_W + dw];
  }
}

// ---------------- Kernel 4: GEMM C[256][16384] = W[256][K] * XcolT[16384][K]^T ---
// 4 waves/block (2x2), wave tile 64x64, no LDS, distance-2 register prefetch.
__global__ __launch_bounds__(256) void k_gemm(const ushort* __restrict__ Wb,
                                              const ushort* __restrict__ Xc,
                                              const float* __restrict__ bias,
                                              float* __restrict__ out) {
  const int bid = blockIdx.x;                 // 0..255
  // swizzle: the two m-tiles of one n-tile land on the same XCD (bid%8 equal)
  const int mtile = (bid >> 3) & 1;
  const int ntile = ((bid >> 4) << 3) | (bid & 7);
  const int wid = threadIdx.x >> 6;
  const int lane = threadIdx.x & 63;
  const int wm = wid & 1, wn = wid >> 1;
  const int m0 = mtile * 128 + wm * 64;
  const int n0 = ntile * 128 + wn * 64;
  const int lrow = lane & 15;
  const int kgrp = lane >> 4;                 // k sub-offset = 8*kgrp

  const ushort* ap[4];
  const ushort* bp[4];
#pragma unroll
  for (int f = 0; f < 4; ++f) {
    ap[f] = Wb + (size_t)(m0 + f * 16 + lrow) * KDIM + kgrp * 8;
    bp[f] = Xc + (size_t)(n0 + f * 16 + lrow) * KDIM + kgrp * 8;
  }

  f32x4 acc[4][4];
#pragma unroll
  for (int i = 0; i < 4; ++i)
#pragma unroll
    for (int j = 0; j < 4; ++j) acc[i][j] = (f32x4){0.f, 0.f, 0.f, 0.f};

  bf16x8 A0[4], B0[4], A1[4], B1[4];
#pragma unroll
  for (int f = 0; f < 4; ++f) {
    A0[f] = *(const bf16x8*)(ap[f]);
    B0[f] = *(const bf16x8*)(bp[f]);
    A1[f] = *(const bf16x8*)(ap[f] + 32);
    B1[f] = *(const bf16x8*)(bp[f] + 32);
  }

  for (int k0 = 0; k0 < KDIM; k0 += 64) {
#pragma unroll
    for (int fm = 0; fm < 4; ++fm)
#pragma unroll
      for (int fn = 0; fn < 4; ++fn)
        acc[fm][fn] = __builtin_amdgcn_mfma_f32_16x16x32_bf16(A0[fm], B0[fn], acc[fm][fn], 0, 0, 0);
    if (k0 + 64 < KDIM) {
#pragma unroll
      for (int f = 0; f < 4; ++f) {
        A0[f] = *(const bf16x8*)(ap[f] + k0 + 64);
        B0[f] = *(const bf16x8*)(bp[f] + k0 + 64);
      }
    }
#pragma unroll
    for (int fm = 0; fm < 4; ++fm)
#pragma unroll
      for (int fn = 0; fn < 4; ++fn)
        acc[fm][fn] = __builtin_amdgcn_mfma_f32_16x16x32_bf16(A1[fm], B1[fn], acc[fm][fn], 0, 0, 0);
    if (k0 + 96 < KDIM) {
#pragma unroll
      for (int f = 0; f < 4; ++f) {
        A1[f] = *(const bf16x8*)(ap[f] + k0 + 96);
        B1[f] = *(const bf16x8*)(bp[f] + k0 + 96);
      }
    }
  }

  // epilogue: D row (oc) = m0+fm*16+4*kgrp+r, col (n) = n0+fn*16+lrow
  f32x4 bv[4];
#pragma unroll
  for (int fm = 0; fm < 4; ++fm)
    bv[fm] = *(const f32x4*)(bias + m0 + fm * 16 + kgrp * 4);

#pragma unroll
  for (int fm = 0; fm < 4; ++fm) {
#pragma unroll
    for (int fn = 0; fn < 4; ++fn) {
      int nn = n0 + fn * 16 + lrow;
      size_t ob = (size_t)(nn >> 10) * OUT_PER_B + (nn & 1023) +
                  (size_t)(m0 + fm * 16 + kgrp * 4) * 1024;
      float* op = out + ob;
      op[0]    = acc[fm][fn][0] + bv[fm][0];
      op[1024] = acc[fm][fn][1] + bv[fm][1];
      op[2048] = acc[fm][fn][2] + bv[fm][2];
      op[3072] = acc[fm][fn][3] + bv[fm][3];
    }
  }
}

extern "C" void kernel_launch(void* const* d_in, const int* in_sizes, int n_in,
                              void* d_out, int out_size, void* d_ws, size_t ws_size,
                              hipStream_t stream) {
  const float* x    = (const float*)d_in[0];  // [16,256,64,64]
  const float* w    = (const float*)d_in[1];  // [256,256,3,3]
  const float* bias = (const float*)d_in[2];  // [256]
  float* out = (float*)d_out;                 // [16,256,32,32]

  char* ws = (char*)d_ws;
  // layout: xf bf16 [4096][4290]  = 35,143,680 B
  //         wb bf16 [256][2304]   =  1,179,648 B
  //         xc bf16 [16384][2304] = 75,497,472 B   (total 111,820,800 B)
  ushort* xf = (ushort*)(ws);
  ushort* wb = (ushort*)(ws + 35143680);
  ushort* xc = (ushort*)(ws + 36323328);

  k_fir<<<4096, 256, 0, stream>>>(x, xf);
  k_wcast<<<576, 256, 0, stream>>>(w, wb);
  k_im2col<<<16384, 256, 0, stream>>>(xf, xc);
  k_gemm<<<256, 256, 0, stream>>>(wb, xc, bias, out);
}